// Round 13
// baseline (436.552 us; speedup 1.0000x reference)
//
#include <hip/hip_runtime.h>
#include <cstdint>
#include <cstddef>

#define N_NODES 32768
#define CIN 256
#define HDIM 512
#define COUT_F 256
#define NTYPE 4
#define ALIGN_SEG 256
#define NPAD (N_NODES + NTYPE * ALIGN_SEG)  // 33792
#define NROWBLK (NPAD / 256)                // 132
#define BN_EPS 1e-5f
#define SLOPE 0.01f

typedef unsigned short u16;
typedef __attribute__((ext_vector_type(8))) short bf16x8;
typedef __attribute__((ext_vector_type(4))) float f32x4;
typedef __attribute__((ext_vector_type(4))) u16 u16x4;

#define GLOBAL_AS __attribute__((address_space(1)))
#define LDS_AS __attribute__((address_space(3)))
#define SBAR() __builtin_amdgcn_s_barrier()
#define SCHED() __builtin_amdgcn_sched_barrier(0)

__device__ __forceinline__ u16 f2bf(float f) {
  union { float f; unsigned u; } v{f};
  unsigned r = (v.u + 0x7FFF + ((v.u >> 16) & 1)) >> 16;  // RNE, finite inputs
  return (u16)r;
}
__device__ __forceinline__ float bf2f(u16 b) {
  union { unsigned u; float f; } v;
  v.u = ((unsigned)b) << 16;
  return v.f;
}

// ---------------- sorting machinery ----------------

__global__ void hist_kernel(const int* __restrict__ nt, int* __restrict__ blockHist) {
  __shared__ int h[NTYPE];
  int tid = threadIdx.x;
  if (tid < NTYPE) h[tid] = 0;
  __syncthreads();
  int i = blockIdx.x * 256 + tid;
  atomicAdd(&h[nt[i]], 1);
  __syncthreads();
  if (tid < NTYPE) blockHist[blockIdx.x * NTYPE + tid] = h[tid];
}

__global__ void scan_kernel(const int* __restrict__ blockHist, int* __restrict__ blockBase,
                            int* __restrict__ meta) {
  int tid = threadIdx.x;
  if (tid < NTYPE) {
    int run = 0;
    for (int b = 0; b < 128; ++b) {
      blockBase[b * NTYPE + tid] = run;
      run += blockHist[b * NTYPE + tid];
    }
    meta[tid] = run;  // per-type count
  }
  __syncthreads();
  if (tid == 0) {
    int s = 0;
    for (int t = 0; t < NTYPE; ++t) {
      meta[4 + t] = s;  // aligned segment start
      s += (meta[t] + ALIGN_SEG - 1) & ~(ALIGN_SEG - 1);
    }
    meta[8] = s;  // padded total
  }
}

// stable rank within 256-chunk -> deterministic permutation
__global__ void rank_scatter_kernel(const int* __restrict__ nt, const int* __restrict__ blockBase,
                                    const int* __restrict__ meta, int* __restrict__ perm) {
  __shared__ int st[256];
  int tid = threadIdx.x;
  int i = blockIdx.x * 256 + tid;
  int t = nt[i];
  st[tid] = t;
  __syncthreads();
  int rank = 0;
  for (int j = 0; j < tid; ++j) rank += (st[j] == t) ? 1 : 0;
  perm[meta[4 + t] + blockBase[blockIdx.x * NTYPE + t] + rank] = i;
}

// xs[p] = bf16(x[perm[p]]) (zeros for padding rows). 256 threads: 4 rows/block.
// XCD-chunked swizzle matches the GEMM consumer's row-tile->XCD mapping so the
// produced rows sit in the same XCD's L2 that will read them (producer/consumer
// L2 alignment; GEMM row-tile by lands on XCD floor(lid/cpx) with the same formula).
__global__ __launch_bounds__(256) void gather_kernel(const float* __restrict__ x,
                                                     const int* __restrict__ perm,
                                                     u16* __restrict__ xs) {
  int nb = (int)gridDim.x;
  int b = (int)blockIdx.x;
  int lid = (b & 7) * (nb >> 3) + (b >> 3);
  int p = lid * 4 + (threadIdx.x >> 6);
  int lane = threadIdx.x & 63;
  int src = perm[p];
  u16x4* dst = (u16x4*)(xs + (size_t)p * CIN);
  if (src < 0) {
    dst[lane] = (u16x4)0;
  } else {
    float4 v = ((const float4*)(x + (size_t)src * CIN))[lane];
    u16x4 o;
    o.x = f2bf(v.x); o.y = f2bf(v.y); o.z = f2bf(v.z); o.w = f2bf(v.w);
    dst[lane] = o;
  }
}

// ---------------- weight transpose + bf16 convert ----------------
// W [T][K][COUT] f32  ->  Wt [T][COUT][K] bf16
template <int K, int COUT>
__global__ __launch_bounds__(256) void wtrans_kernel(const float* __restrict__ W,
                                                     u16* __restrict__ Wt) {
  const int t = blockIdx.z;
  const int k0 = blockIdx.x * 32, c0 = blockIdx.y * 32;
  const float* __restrict__ Ws = W + (size_t)t * K * COUT;
  u16* __restrict__ Wd = Wt + (size_t)t * COUT * K;
  __shared__ float tile[32][33];
  int tid = threadIdx.x;
#pragma unroll
  for (int p = 0; p < 4; ++p) {
    int idx = p * 256 + tid;
    int r = idx >> 5, c = idx & 31;
    tile[r][c] = Ws[(size_t)(k0 + r) * COUT + c0 + c];
  }
  __syncthreads();
#pragma unroll
  for (int p = 0; p < 4; ++p) {
    int idx = p * 256 + tid;
    int r = idx >> 5, c = idx & 31;
    Wd[(size_t)(c0 + r) * K + k0 + c] = f2bf(tile[c][r]);
  }
}

// ---------------- bf16 MFMA GEMM: 256x128 tile, BK=32, 8 waves, dbuf + counted vmcnt ----
// r12 best-known skeleton (166.3us). This round: __launch_bounds__(512,6) -> VGPR cap
// ~85 so THREE blocks/CU fit (LDS 48KB x3 = 144 <= 160KB; 24 waves/CU). Grid 528 then
// runs as ONE fully-resident round (capacity 768) with 3-way cross-block stall overlap.
// LDS row = 32 elems (64B). Chunk swizzle u = c ^ ((r>>1)&3), applied on the GLOBAL
// source (LDS stays linear for global_load_lds); ds_read_b128 worst case 2-way (free).
// Staging per thread per K-tile: 2 A + 1 B global_load_lds -> counted vmcnt(3).

template <int K, int COUT, bool SCATTER, bool STATS>
__global__ __launch_bounds__(512, 6) void mfma_gemm_kernel(
    const u16* __restrict__ A, const u16* __restrict__ Wt, const float* __restrict__ bias,
    u16* __restrict__ Yb, float* __restrict__ Yf, float* __restrict__ partS,
    float* __restrict__ partQ, const int* __restrict__ meta, const int* __restrict__ perm) {
  constexpr int GX = COUT / 128;
  constexpr int ASZ = 256 * 32;  // elems per A buffer (16 KB)
  constexpr int BSZ = 128 * 32;  // elems per B buffer (8 KB)
  const int nwg = (int)(gridDim.x * gridDim.y);
  int l = (int)(blockIdx.y * gridDim.x + blockIdx.x);
  int lid = (l & 7) * (nwg >> 3) + (l >> 3);
  const int bx = lid % GX, by = lid / GX;
  const int col0 = bx * 128, row0 = by * 256;

  const int s1 = meta[5], s2 = meta[6], s3 = meta[7];
  const int t = row0 >= s3 ? 3 : (row0 >= s2 ? 2 : (row0 >= s1 ? 1 : 0));
  const int seg_end = meta[4 + t] + meta[t];
  const u16* __restrict__ Bt = Wt + (size_t)t * COUT * K;

  __shared__ __align__(16) u16 As[2][ASZ];
  __shared__ __align__(16) u16 Bs[2][BSZ];

  const int tid = threadIdx.x;
  const int lane = tid & 63;
  const int lr = lane & 15, ls = lane >> 4;
  const int wid = tid >> 6;
  const int wm = wid >> 1, wn = wid & 1;  // 4 M-waves x 2 N-waves

  // fragment LDS element offsets: row r, logical octet ls, phys octet ls ^ ((r>>1)&3)
  int a_off[4], b_off[4];
#pragma unroll
  for (int i = 0; i < 4; ++i) {
    int r = wm * 64 + i * 16 + lr;
    a_off[i] = r * 32 + (ls ^ ((r >> 1) & 3)) * 8;
  }
#pragma unroll
  for (int j = 0; j < 4; ++j) {
    int r = wn * 64 + j * 16 + lr;
    b_off[j] = r * 32 + (ls ^ ((r >> 1) & 3)) * 8;
  }

  // staging: LDS chunk lch (linear, 16B each); global octet c = (lch&3) ^ ((r>>1)&3)
  int stA_row[2], stA_col[2];
#pragma unroll
  for (int p = 0; p < 2; ++p) {
    int lch = p * 512 + tid;
    int r = lch >> 2;
    stA_row[p] = r;
    stA_col[p] = ((lch & 3) ^ ((r >> 1) & 3)) * 8;
  }
  const int stB_row = tid >> 2;
  const int stB_col = ((tid & 3) ^ ((stB_row >> 1) & 3)) * 8;
  const int ldsW = (tid & 448) * 8;  // wave-uniform base (elems)

  const int nsteps = K / 32;

  auto stage = [&](int buf, int k0) {
#pragma unroll
    for (int p = 0; p < 2; ++p) {
      const u16* ga = A + (size_t)(row0 + stA_row[p]) * K + k0 + stA_col[p];
      __builtin_amdgcn_global_load_lds((const GLOBAL_AS void*)ga,
                                       (LDS_AS void*)(&As[buf][0] + p * 4096 + ldsW), 16, 0, 0);
    }
    const u16* gb = Bt + (size_t)(col0 + stB_row) * K + k0 + stB_col;
    __builtin_amdgcn_global_load_lds((const GLOBAL_AS void*)gb,
                                     (LDS_AS void*)(&Bs[buf][0] + ldsW), 16, 0, 0);
  };

  f32x4 acc[4][4] = {};

  stage(0, 0);
  for (int t8 = 0; t8 < nsteps; ++t8) {
    const int cur = t8 & 1;
    if (t8 + 1 < nsteps) {
      stage(cur ^ 1, (t8 + 1) * 32);
      asm volatile("s_waitcnt vmcnt(3)" ::: "memory");  // tile t ready; next 3 in flight
    } else {
      asm volatile("s_waitcnt vmcnt(0)" ::: "memory");
    }
    SBAR();
    SCHED();
    bf16x8 af[4], bfr[4];
#pragma unroll
    for (int i = 0; i < 4; ++i) af[i] = *(const bf16x8*)(&As[cur][0] + a_off[i]);
#pragma unroll
    for (int j = 0; j < 4; ++j) bfr[j] = *(const bf16x8*)(&Bs[cur][0] + b_off[j]);
#pragma unroll
    for (int i = 0; i < 4; ++i)
#pragma unroll
      for (int j = 0; j < 4; ++j)
        acc[i][j] = __builtin_amdgcn_mfma_f32_16x16x32_bf16(af[i], bfr[j], acc[i][j], 0, 0, 0);
    SBAR();  // all waves done reading buf[cur] before re-stage
    SCHED();
  }

  // epilogue. C/D: col = lane&15 (lr), row = ls*4 + reg.
  float bj[4];
#pragma unroll
  for (int j = 0; j < 4; ++j) bj[j] = bias[(size_t)t * COUT + col0 + wn * 64 + j * 16 + lr];

  if (SCATTER) {
#pragma unroll
    for (int i = 0; i < 4; ++i) {
      int rbase = row0 + wm * 64 + i * 16 + ls * 4;
      int dsts[4];
#pragma unroll
      for (int r = 0; r < 4; ++r) dsts[r] = perm[rbase + r];
#pragma unroll
      for (int j = 0; j < 4; ++j) {
        int gcol = col0 + wn * 64 + j * 16 + lr;
#pragma unroll
        for (int r = 0; r < 4; ++r) {
          if (dsts[r] >= 0) Yf[(size_t)dsts[r] * COUT + gcol] = acc[i][j][r] + bj[j];
        }
      }
    }
  } else {
    float s[4] = {}, q[4] = {};
#pragma unroll
    for (int i = 0; i < 4; ++i) {
      int rbase = row0 + wm * 64 + i * 16 + ls * 4;
#pragma unroll
      for (int j = 0; j < 4; ++j) {
        int gcol = col0 + wn * 64 + j * 16 + lr;
#pragma unroll
        for (int r = 0; r < 4; ++r) {
          int row = rbase + r;
          float y = acc[i][j][r] + bj[j];
          Yb[(size_t)row * COUT + gcol] = f2bf(y);
          if (STATS && row < seg_end) {
            s[j] += y;
            q[j] += y * y;
          }
        }
      }
    }
    if (STATS) {
      // deterministic block-level column reduction via LDS (reuse As/Bs)
      float* sred = (float*)&As[0][0];  // [16][128] floats = 8 KB
      float* qred = (float*)&Bs[0][0];  // [16][128] floats = 8 KB
      int grp = wm * 4 + ls;  // 0..15
      __syncthreads();
#pragma unroll
      for (int j = 0; j < 4; ++j) {
        int colIdx = wn * 64 + j * 16 + lr;
        sred[grp * 128 + colIdx] = s[j];
        qred[grp * 128 + colIdx] = q[j];
      }
      __syncthreads();
      if (tid < 128) {
        float S = 0.f, Q = 0.f;
#pragma unroll
        for (int k = 0; k < 16; ++k) {
          S += sred[k * 128 + tid];
          Q += qred[k * 128 + tid];
        }
        partS[(size_t)by * COUT + col0 + tid] = S;
        partQ[(size_t)by * COUT + col0 + tid] = Q;
      }
    }
  }
}

// ---------------- BN finalize (sum per-rowblock partials per segment) ----------------

__global__ __launch_bounds__(256) void bn_finalize_kernel(const float* __restrict__ partS,
                                                          const float* __restrict__ partQ,
                                                          const int* __restrict__ meta,
                                                          float* __restrict__ mean,
                                                          float* __restrict__ rstd) {
  int idx = blockIdx.x * 256 + threadIdx.x;  // 0 .. NTYPE*HDIM-1
  int t = idx >> 9;
  int c = idx & (HDIM - 1);
  int start = meta[4 + t];
  int cnt = meta[t];
  int b0 = start >> 8;
  int nb = (cnt + 255) >> 8;
  float S = 0.f, Q = 0.f;
  for (int b = 0; b < nb; ++b) {
    S += partS[(size_t)(b0 + b) * HDIM + c];
    Q += partQ[(size_t)(b0 + b) * HDIM + c];
  }
  float n = (float)(cnt > 1 ? cnt : 1);
  float m = S / n;
  float var = Q / n - m * m;
  mean[idx] = m;
  rstd[idx] = rsqrtf(fmaxf(var, 0.f) + BN_EPS);
}

// ---------------- BN apply (bf16 in -> normalize+leaky -> bf16 out) ----------------
// XCD-chunked swizzle: rows it writes land on the same XCD's L2 as the GEMM that
// will read them (same chunk formula as the GEMM grid swizzle).

__global__ __launch_bounds__(256) void bn_apply_kernel(
    const u16* __restrict__ h, const int* __restrict__ meta, const float* __restrict__ mean,
    const float* __restrict__ rstd, const float* __restrict__ gamma,
    const float* __restrict__ beta, u16* __restrict__ aout) {
  int nb = (int)gridDim.x;
  int b = (int)blockIdx.x;
  int lid = (b & 7) * (nb >> 3) + (b >> 3);
  int idx = lid * 256 + threadIdx.x;  // 8-elem groups
  int row = idx >> 6;                 // HDIM/8 = 64 groups per row
  int g8 = (idx & 63) * 8;
  const int s1 = meta[5], s2 = meta[6], s3 = meta[7];
  const int t = row >= s3 ? 3 : (row >= s2 ? 2 : (row >= s1 ? 1 : 0));
  size_t base = (size_t)row * HDIM + g8;
  uint4 v = *(const uint4*)(h + base);
  unsigned w[4] = {v.x, v.y, v.z, v.w};
  int tb = t * HDIM + g8;
  float mv[8], rv[8], gv[8], bv[8];
  *(float4*)&mv[0] = *(const float4*)(mean + tb);
  *(float4*)&mv[4] = *(const float4*)(mean + tb + 4);
  *(float4*)&rv[0] = *(const float4*)(rstd + tb);
  *(float4*)&rv[4] = *(const float4*)(rstd + tb + 4);
  *(float4*)&gv[0] = *(const float4*)(gamma + tb);
  *(float4*)&gv[4] = *(const float4*)(gamma + tb + 4);
  *(float4*)&bv[0] = *(const float4*)(beta + tb);
  *(float4*)&bv[4] = *(const float4*)(beta + tb + 4);
  unsigned o[4];
#pragma unroll
  for (int p = 0; p < 4; ++p) {
    u16 lo = (u16)(w[p] & 0xFFFF), hi = (u16)(w[p] >> 16);
    int e0 = p * 2, e1 = p * 2 + 1;
    float sc0 = rv[e0] * gv[e0], sc1 = rv[e1] * gv[e1];
    float y0 = bf2f(lo) * sc0 + (bv[e0] - mv[e0] * sc0);
    float y1 = bf2f(hi) * sc1 + (bv[e1] - mv[e1] * sc1);
    y0 = y0 >= 0.f ? y0 : SLOPE * y0;
    y1 = y1 >= 0.f ? y1 : SLOPE * y1;
    o[p] = (unsigned)f2bf(y0) | ((unsigned)f2bf(y1) << 16);
  }
  *(uint4*)(aout + base) = make_uint4(o[0], o[1], o[2], o[3]);
}

// ---------------- launch ----------------

extern "C" void kernel_launch(void* const* d_in, const int* in_sizes, int n_in, void* d_out,
                              int out_size, void* d_ws, size_t ws_size, hipStream_t stream) {
  const float* x = (const float*)d_in[0];
  const int* nt = (const int*)d_in[1];
  const float* W1 = (const float*)d_in[2];
  const float* b1 = (const float*)d_in[3];
  const float* W2 = (const float*)d_in[4];
  const float* b2 = (const float*)d_in[5];
  const float* W3 = (const float*)d_in[6];
  const float* b3 = (const float*)d_in[7];
  const float* g1 = (const float*)d_in[8];
  const float* be1 = (const float*)d_in[9];
  const float* g2 = (const float*)d_in[10];
  const float* be2 = (const float*)d_in[11];
  float* out = (float*)d_out;

  char* ws = (char*)d_ws;
  size_t off = 0;
  auto alloc = [&](size_t bytes) {
    void* p = ws + off;
    off = (off + bytes + 255) & ~(size_t)255;
    return p;
  };
  int* meta = (int*)alloc(16 * 4);
  int* blockHist = (int*)alloc(128 * NTYPE * 4);
  int* blockBase = (int*)alloc(128 * NTYPE * 4);
  int* perm = (int*)alloc((size_t)NPAD * 4);
  float* mean = (float*)alloc((size_t)NTYPE * HDIM * 4);
  float* rstd = (float*)alloc((size_t)NTYPE * HDIM * 4);
  float* partS = (float*)alloc((size_t)NROWBLK * HDIM * 4);
  float* partQ = (float*)alloc((size_t)NROWBLK * HDIM * 4);
  u16* Wt1 = (u16*)alloc((size_t)NTYPE * CIN * HDIM * 2);
  u16* Wt2 = (u16*)alloc((size_t)NTYPE * HDIM * HDIM * 2);
  u16* Wt3 = (u16*)alloc((size_t)NTYPE * HDIM * COUT_F * 2);
  u16* xs = (u16*)alloc((size_t)NPAD * CIN * 2);     // bf16 layer-1 input
  u16* abuf = (u16*)alloc((size_t)NPAD * HDIM * 2);  // bf16 activations
  u16* hb = (u16*)alloc((size_t)NPAD * HDIM * 2);    // bf16 pre-BN

  hipMemsetAsync(meta, 0, 64, stream);
  hipMemsetAsync(perm, 0xFF, (size_t)NPAD * 4, stream);
  hist_kernel<<<128, 256, 0, stream>>>(nt, blockHist);
  scan_kernel<<<1, 64, 0, stream>>>(blockHist, blockBase, meta);
  rank_scatter_kernel<<<128, 256, 0, stream>>>(nt, blockBase, meta, perm);
  gather_kernel<<<NPAD / 4, 256, 0, stream>>>(x, perm, xs);

  wtrans_kernel<CIN, HDIM><<<dim3(CIN / 32, HDIM / 32, NTYPE), 256, 0, stream>>>(W1, Wt1);
  wtrans_kernel<HDIM, HDIM><<<dim3(HDIM / 32, HDIM / 32, NTYPE), 256, 0, stream>>>(W2, Wt2);
  wtrans_kernel<HDIM, COUT_F><<<dim3(HDIM / 32, COUT_F / 32, NTYPE), 256, 0, stream>>>(W3, Wt3);

  // Layer 1: GEMM + fused stats (grid 4x132 = 528; 3 blocks/CU -> one resident round)
  mfma_gemm_kernel<CIN, HDIM, false, true>
      <<<dim3(HDIM / 128, NPAD / 256), 512, 0, stream>>>(xs, Wt1, b1, hb, nullptr, partS, partQ,
                                                         meta, nullptr);
  bn_finalize_kernel<<<(NTYPE * HDIM) / 256, 256, 0, stream>>>(partS, partQ, meta, mean, rstd);
  bn_apply_kernel<<<(NPAD * (HDIM / 8)) / 256, 256, 0, stream>>>(hb, meta, mean, rstd, g1, be1,
                                                                 abuf);
  // Layer 2 (grid 528)
  mfma_gemm_kernel<HDIM, HDIM, false, true>
      <<<dim3(HDIM / 128, NPAD / 256), 512, 0, stream>>>(abuf, Wt2, b2, hb, nullptr, partS, partQ,
                                                         meta, nullptr);
  bn_finalize_kernel<<<(NTYPE * HDIM) / 256, 256, 0, stream>>>(partS, partQ, meta, mean, rstd);
  bn_apply_kernel<<<(NPAD * (HDIM / 8)) / 256, 256, 0, stream>>>(hb, meta, mean, rstd, g2, be2,
                                                                 abuf);
  // Layer 3 (scatter to d_out, fp32; grid 2x132 = 264)
  mfma_gemm_kernel<HDIM, COUT_F, true, false>
      <<<dim3(COUT_F / 128, NPAD / 256), 512, 0, stream>>>(abuf, Wt3, b3, nullptr, out, nullptr,
                                                           nullptr, meta, perm);
}

// Round 14
// 164.840 us; speedup vs baseline: 2.6483x; 2.6483x over previous
//
#include <hip/hip_runtime.h>
#include <cstdint>
#include <cstddef>

#define N_NODES 32768
#define CIN 256
#define HDIM 512
#define COUT_F 256
#define NTYPE 4
#define ALIGN_SEG 256
#define NPAD (N_NODES + NTYPE * ALIGN_SEG)  // 33792
#define NROWBLK (NPAD / 128)                // 264
#define BN_EPS 1e-5f
#define SLOPE 0.01f

typedef unsigned short u16;
typedef __attribute__((ext_vector_type(8))) short bf16x8;
typedef __attribute__((ext_vector_type(4))) float f32x4;
typedef __attribute__((ext_vector_type(4))) u16 u16x4;

#define GLOBAL_AS __attribute__((address_space(1)))
#define LDS_AS __attribute__((address_space(3)))
#define SBAR() __builtin_amdgcn_s_barrier()
#define SCHED() __builtin_amdgcn_sched_barrier(0)

__device__ __forceinline__ u16 f2bf(float f) {
  union { float f; unsigned u; } v{f};
  unsigned r = (v.u + 0x7FFF + ((v.u >> 16) & 1)) >> 16;  // RNE, finite inputs
  return (u16)r;
}
__device__ __forceinline__ float bf2f(u16 b) {
  union { unsigned u; float f; } v;
  v.u = ((unsigned)b) << 16;
  return v.f;
}

// ---------------- sorting machinery ----------------

__global__ void hist_kernel(const int* __restrict__ nt, int* __restrict__ blockHist) {
  __shared__ int h[NTYPE];
  int tid = threadIdx.x;
  if (tid < NTYPE) h[tid] = 0;
  __syncthreads();
  int i = blockIdx.x * 256 + tid;
  atomicAdd(&h[nt[i]], 1);
  __syncthreads();
  if (tid < NTYPE) blockHist[blockIdx.x * NTYPE + tid] = h[tid];
}

__global__ void scan_kernel(const int* __restrict__ blockHist, int* __restrict__ blockBase,
                            int* __restrict__ meta) {
  int tid = threadIdx.x;
  if (tid < NTYPE) {
    int run = 0;
    for (int b = 0; b < 128; ++b) {
      blockBase[b * NTYPE + tid] = run;
      run += blockHist[b * NTYPE + tid];
    }
    meta[tid] = run;  // per-type count
  }
  __syncthreads();
  if (tid == 0) {
    int s = 0;
    for (int t = 0; t < NTYPE; ++t) {
      meta[4 + t] = s;  // aligned segment start
      s += (meta[t] + ALIGN_SEG - 1) & ~(ALIGN_SEG - 1);
    }
    meta[8] = s;  // padded total
  }
}

// stable rank within 256-chunk -> deterministic permutation
__global__ void rank_scatter_kernel(const int* __restrict__ nt, const int* __restrict__ blockBase,
                                    const int* __restrict__ meta, int* __restrict__ perm) {
  __shared__ int st[256];
  int tid = threadIdx.x;
  int i = blockIdx.x * 256 + tid;
  int t = nt[i];
  st[tid] = t;
  __syncthreads();
  int rank = 0;
  for (int j = 0; j < tid; ++j) rank += (st[j] == t) ? 1 : 0;
  perm[meta[4 + t] + blockBase[blockIdx.x * NTYPE + t] + rank] = i;
}

// xs[p] = bf16(x[perm[p]]) (zeros for padding rows). 256 threads: 4 rows/block.
// XCD-chunked swizzle keeps producer rows on the consumer GEMM's XCD L2.
__global__ __launch_bounds__(256) void gather_kernel(const float* __restrict__ x,
                                                     const int* __restrict__ perm,
                                                     u16* __restrict__ xs) {
  int nb = (int)gridDim.x;
  int b = (int)blockIdx.x;
  int lid = (b & 7) * (nb >> 3) + (b >> 3);
  int p = lid * 4 + (threadIdx.x >> 6);
  int lane = threadIdx.x & 63;
  int src = perm[p];
  u16x4* dst = (u16x4*)(xs + (size_t)p * CIN);
  if (src < 0) {
    dst[lane] = (u16x4)0;
  } else {
    float4 v = ((const float4*)(x + (size_t)src * CIN))[lane];
    u16x4 o;
    o.x = f2bf(v.x); o.y = f2bf(v.y); o.z = f2bf(v.z); o.w = f2bf(v.w);
    dst[lane] = o;
  }
}

// ---------------- weight transpose + bf16 convert ----------------
// W [T][K][COUT] f32  ->  Wt [T][COUT][K] bf16
template <int K, int COUT>
__global__ __launch_bounds__(256) void wtrans_kernel(const float* __restrict__ W,
                                                     u16* __restrict__ Wt) {
  const int t = blockIdx.z;
  const int k0 = blockIdx.x * 32, c0 = blockIdx.y * 32;
  const float* __restrict__ Ws = W + (size_t)t * K * COUT;
  u16* __restrict__ Wd = Wt + (size_t)t * COUT * K;
  __shared__ float tile[32][33];
  int tid = threadIdx.x;
#pragma unroll
  for (int p = 0; p < 4; ++p) {
    int idx = p * 256 + tid;
    int r = idx >> 5, c = idx & 31;
    tile[r][c] = Ws[(size_t)(k0 + r) * COUT + c0 + c];
  }
  __syncthreads();
#pragma unroll
  for (int p = 0; p < 4; ++p) {
    int idx = p * 256 + tid;
    int r = idx >> 5, c = idx & 31;
    Wd[(size_t)(c0 + r) * K + k0 + c] = f2bf(tile[c][r]);
  }
}

// ---------------- bf16 MFMA GEMM: 128x128 tile, BK=32, 4 waves, dbuf + counted vmcnt ----
// r12 skeleton (166.3us best) with geometry-driven residency: 128x128 tile, 256 threads
// (4 waves 2Mx2N, per-wave 64x64 = same acc footprint as r12 -> natural VGPR ~88, NO
// launch-bounds cap after the r13 spill disaster: (512,6) forced VGPR 40 -> 440MB
// scratch traffic). LDS 32KB/block -> 5 blocks/CU by LDS; VGPR 88 -> 5 waves/SIMD ->
// 5 blocks/CU. Grid 1056 <= capacity 1280 -> ONE resident round, 5-way stall overlap.
// LDS row = 32 elems (64B). Chunk swizzle u = c ^ ((r>>1)&3) on the GLOBAL source
// (LDS linear for global_load_lds); ds_read_b128 worst 2-way (free).
// Staging per thread per K-tile: 2 A + 2 B global_load_lds -> counted vmcnt(4).

template <int K, int COUT, bool SCATTER, bool STATS>
__global__ __launch_bounds__(256) void mfma_gemm_kernel(
    const u16* __restrict__ A, const u16* __restrict__ Wt, const float* __restrict__ bias,
    u16* __restrict__ Yb, float* __restrict__ Yf, float* __restrict__ partS,
    float* __restrict__ partQ, const int* __restrict__ meta, const int* __restrict__ perm) {
  constexpr int GX = COUT / 128;
  constexpr int ASZ = 128 * 32;  // elems per A buffer (8 KB)
  constexpr int BSZ = 128 * 32;  // elems per B buffer (8 KB)
  const int nwg = (int)(gridDim.x * gridDim.y);
  int l = (int)(blockIdx.y * gridDim.x + blockIdx.x);
  int lid = (l & 7) * (nwg >> 3) + (l >> 3);
  const int bx = lid % GX, by = lid / GX;
  const int col0 = bx * 128, row0 = by * 128;

  const int s1 = meta[5], s2 = meta[6], s3 = meta[7];
  const int t = row0 >= s3 ? 3 : (row0 >= s2 ? 2 : (row0 >= s1 ? 1 : 0));
  const int seg_end = meta[4 + t] + meta[t];
  const u16* __restrict__ Bt = Wt + (size_t)t * COUT * K;

  __shared__ __align__(16) u16 As[2][ASZ];
  __shared__ __align__(16) u16 Bs[2][BSZ];

  const int tid = threadIdx.x;
  const int lane = tid & 63;
  const int lr = lane & 15, ls = lane >> 4;
  const int wid = tid >> 6;           // 0..3
  const int wm = wid >> 1, wn = wid & 1;  // 2 M-waves x 2 N-waves

  // fragment LDS element offsets: row r, logical octet ls, phys octet ls ^ ((r>>1)&3)
  int a_off[4], b_off[4];
#pragma unroll
  for (int i = 0; i < 4; ++i) {
    int r = wm * 64 + i * 16 + lr;
    a_off[i] = r * 32 + (ls ^ ((r >> 1) & 3)) * 8;
  }
#pragma unroll
  for (int j = 0; j < 4; ++j) {
    int r = wn * 64 + j * 16 + lr;
    b_off[j] = r * 32 + (ls ^ ((r >> 1) & 3)) * 8;
  }

  // staging: LDS chunk lch = p*256+tid (linear, 16B each); global octet c=(lch&3)^((r>>1)&3)
  int st_row[2], st_col[2];
#pragma unroll
  for (int p = 0; p < 2; ++p) {
    int lch = p * 256 + tid;
    int r = lch >> 2;
    st_row[p] = r;
    st_col[p] = ((lch & 3) ^ ((r >> 1) & 3)) * 8;
  }
  const int ldsW = (tid & 192) * 8;  // wave-uniform base (elems)

  const int nsteps = K / 32;

  auto stage = [&](int buf, int k0) {
#pragma unroll
    for (int p = 0; p < 2; ++p) {
      const u16* ga = A + (size_t)(row0 + st_row[p]) * K + k0 + st_col[p];
      __builtin_amdgcn_global_load_lds((const GLOBAL_AS void*)ga,
                                       (LDS_AS void*)(&As[buf][0] + p * 2048 + ldsW), 16, 0, 0);
    }
#pragma unroll
    for (int p = 0; p < 2; ++p) {
      const u16* gb = Bt + (size_t)(col0 + st_row[p]) * K + k0 + st_col[p];
      __builtin_amdgcn_global_load_lds((const GLOBAL_AS void*)gb,
                                       (LDS_AS void*)(&Bs[buf][0] + p * 2048 + ldsW), 16, 0, 0);
    }
  };

  f32x4 acc[4][4] = {};

  stage(0, 0);
  for (int t8 = 0; t8 < nsteps; ++t8) {
    const int cur = t8 & 1;
    if (t8 + 1 < nsteps) {
      stage(cur ^ 1, (t8 + 1) * 32);
      asm volatile("s_waitcnt vmcnt(4)" ::: "memory");  // tile t ready; next 4 in flight
    } else {
      asm volatile("s_waitcnt vmcnt(0)" ::: "memory");
    }
    SBAR();
    SCHED();
    bf16x8 af[4], bfr[4];
#pragma unroll
    for (int i = 0; i < 4; ++i) af[i] = *(const bf16x8*)(&As[cur][0] + a_off[i]);
#pragma unroll
    for (int j = 0; j < 4; ++j) bfr[j] = *(const bf16x8*)(&Bs[cur][0] + b_off[j]);
#pragma unroll
    for (int i = 0; i < 4; ++i)
#pragma unroll
      for (int j = 0; j < 4; ++j)
        acc[i][j] = __builtin_amdgcn_mfma_f32_16x16x32_bf16(af[i], bfr[j], acc[i][j], 0, 0, 0);
    SBAR();  // all waves done reading buf[cur] before re-stage
    SCHED();
  }

  // epilogue. C/D: col = lane&15 (lr), row = ls*4 + reg.
  float bj[4];
#pragma unroll
  for (int j = 0; j < 4; ++j) bj[j] = bias[(size_t)t * COUT + col0 + wn * 64 + j * 16 + lr];

  if (SCATTER) {
#pragma unroll
    for (int i = 0; i < 4; ++i) {
      int rbase = row0 + wm * 64 + i * 16 + ls * 4;
      int dsts[4];
#pragma unroll
      for (int r = 0; r < 4; ++r) dsts[r] = perm[rbase + r];
#pragma unroll
      for (int j = 0; j < 4; ++j) {
        int gcol = col0 + wn * 64 + j * 16 + lr;
#pragma unroll
        for (int r = 0; r < 4; ++r) {
          if (dsts[r] >= 0) Yf[(size_t)dsts[r] * COUT + gcol] = acc[i][j][r] + bj[j];
        }
      }
    }
  } else {
    float s[4] = {}, q[4] = {};
#pragma unroll
    for (int i = 0; i < 4; ++i) {
      int rbase = row0 + wm * 64 + i * 16 + ls * 4;
#pragma unroll
      for (int j = 0; j < 4; ++j) {
        int gcol = col0 + wn * 64 + j * 16 + lr;
#pragma unroll
        for (int r = 0; r < 4; ++r) {
          int row = rbase + r;
          float y = acc[i][j][r] + bj[j];
          Yb[(size_t)row * COUT + gcol] = f2bf(y);
          if (STATS && row < seg_end) {
            s[j] += y;
            q[j] += y * y;
          }
        }
      }
    }
    if (STATS) {
      // deterministic block-level column reduction via LDS (reuse As/Bs)
      float* sred = (float*)&As[0][0];  // [8][128] floats = 4 KB
      float* qred = (float*)&Bs[0][0];  // [8][128] floats = 4 KB
      int grp = wm * 4 + ls;  // 0..7
      __syncthreads();
#pragma unroll
      for (int j = 0; j < 4; ++j) {
        int colIdx = wn * 64 + j * 16 + lr;
        sred[grp * 128 + colIdx] = s[j];
        qred[grp * 128 + colIdx] = q[j];
      }
      __syncthreads();
      if (tid < 128) {
        float S = 0.f, Q = 0.f;
#pragma unroll
        for (int k = 0; k < 8; ++k) {
          S += sred[k * 128 + tid];
          Q += qred[k * 128 + tid];
        }
        partS[(size_t)by * COUT + col0 + tid] = S;
        partQ[(size_t)by * COUT + col0 + tid] = Q;
      }
    }
  }
}

// ---------------- BN finalize (sum per-rowblock partials per segment) ----------------

__global__ __launch_bounds__(256) void bn_finalize_kernel(const float* __restrict__ partS,
                                                          const float* __restrict__ partQ,
                                                          const int* __restrict__ meta,
                                                          float* __restrict__ mean,
                                                          float* __restrict__ rstd) {
  int idx = blockIdx.x * 256 + threadIdx.x;  // 0 .. NTYPE*HDIM-1
  int t = idx >> 9;
  int c = idx & (HDIM - 1);
  int start = meta[4 + t];
  int cnt = meta[t];
  int b0 = start >> 7;
  int nb = (cnt + 127) >> 7;
  float S = 0.f, Q = 0.f;
  for (int b = 0; b < nb; ++b) {
    S += partS[(size_t)(b0 + b) * HDIM + c];
    Q += partQ[(size_t)(b0 + b) * HDIM + c];
  }
  float n = (float)(cnt > 1 ? cnt : 1);
  float m = S / n;
  float var = Q / n - m * m;
  mean[idx] = m;
  rstd[idx] = rsqrtf(fmaxf(var, 0.f) + BN_EPS);
}

// ---------------- BN apply (bf16 in -> normalize+leaky -> bf16 out) ----------------
// XCD-chunked swizzle aligns written rows with the consumer GEMM's XCD L2.

__global__ __launch_bounds__(256) void bn_apply_kernel(
    const u16* __restrict__ h, const int* __restrict__ meta, const float* __restrict__ mean,
    const float* __restrict__ rstd, const float* __restrict__ gamma,
    const float* __restrict__ beta, u16* __restrict__ aout) {
  int nb = (int)gridDim.x;
  int b = (int)blockIdx.x;
  int lid = (b & 7) * (nb >> 3) + (b >> 3);
  int idx = lid * 256 + threadIdx.x;  // 8-elem groups
  int row = idx >> 6;                 // HDIM/8 = 64 groups per row
  int g8 = (idx & 63) * 8;
  const int s1 = meta[5], s2 = meta[6], s3 = meta[7];
  const int t = row >= s3 ? 3 : (row >= s2 ? 2 : (row >= s1 ? 1 : 0));
  size_t base = (size_t)row * HDIM + g8;
  uint4 v = *(const uint4*)(h + base);
  unsigned w[4] = {v.x, v.y, v.z, v.w};
  int tb = t * HDIM + g8;
  float mv[8], rv[8], gv[8], bv[8];
  *(float4*)&mv[0] = *(const float4*)(mean + tb);
  *(float4*)&mv[4] = *(const float4*)(mean + tb + 4);
  *(float4*)&rv[0] = *(const float4*)(rstd + tb);
  *(float4*)&rv[4] = *(const float4*)(rstd + tb + 4);
  *(float4*)&gv[0] = *(const float4*)(gamma + tb);
  *(float4*)&gv[4] = *(const float4*)(gamma + tb + 4);
  *(float4*)&bv[0] = *(const float4*)(beta + tb);
  *(float4*)&bv[4] = *(const float4*)(beta + tb + 4);
  unsigned o[4];
#pragma unroll
  for (int p = 0; p < 4; ++p) {
    u16 lo = (u16)(w[p] & 0xFFFF), hi = (u16)(w[p] >> 16);
    int e0 = p * 2, e1 = p * 2 + 1;
    float sc0 = rv[e0] * gv[e0], sc1 = rv[e1] * gv[e1];
    float y0 = bf2f(lo) * sc0 + (bv[e0] - mv[e0] * sc0);
    float y1 = bf2f(hi) * sc1 + (bv[e1] - mv[e1] * sc1);
    y0 = y0 >= 0.f ? y0 : SLOPE * y0;
    y1 = y1 >= 0.f ? y1 : SLOPE * y1;
    o[p] = (unsigned)f2bf(y0) | ((unsigned)f2bf(y1) << 16);
  }
  *(uint4*)(aout + base) = make_uint4(o[0], o[1], o[2], o[3]);
}

// ---------------- launch ----------------

extern "C" void kernel_launch(void* const* d_in, const int* in_sizes, int n_in, void* d_out,
                              int out_size, void* d_ws, size_t ws_size, hipStream_t stream) {
  const float* x = (const float*)d_in[0];
  const int* nt = (const int*)d_in[1];
  const float* W1 = (const float*)d_in[2];
  const float* b1 = (const float*)d_in[3];
  const float* W2 = (const float*)d_in[4];
  const float* b2 = (const float*)d_in[5];
  const float* W3 = (const float*)d_in[6];
  const float* b3 = (const float*)d_in[7];
  const float* g1 = (const float*)d_in[8];
  const float* be1 = (const float*)d_in[9];
  const float* g2 = (const float*)d_in[10];
  const float* be2 = (const float*)d_in[11];
  float* out = (float*)d_out;

  char* ws = (char*)d_ws;
  size_t off = 0;
  auto alloc = [&](size_t bytes) {
    void* p = ws + off;
    off = (off + bytes + 255) & ~(size_t)255;
    return p;
  };
  int* meta = (int*)alloc(16 * 4);
  int* blockHist = (int*)alloc(128 * NTYPE * 4);
  int* blockBase = (int*)alloc(128 * NTYPE * 4);
  int* perm = (int*)alloc((size_t)NPAD * 4);
  float* mean = (float*)alloc((size_t)NTYPE * HDIM * 4);
  float* rstd = (float*)alloc((size_t)NTYPE * HDIM * 4);
  float* partS = (float*)alloc((size_t)NROWBLK * HDIM * 4);
  float* partQ = (float*)alloc((size_t)NROWBLK * HDIM * 4);
  u16* Wt1 = (u16*)alloc((size_t)NTYPE * CIN * HDIM * 2);
  u16* Wt2 = (u16*)alloc((size_t)NTYPE * HDIM * HDIM * 2);
  u16* Wt3 = (u16*)alloc((size_t)NTYPE * HDIM * COUT_F * 2);
  u16* xs = (u16*)alloc((size_t)NPAD * CIN * 2);     // bf16 layer-1 input
  u16* abuf = (u16*)alloc((size_t)NPAD * HDIM * 2);  // bf16 activations
  u16* hb = (u16*)alloc((size_t)NPAD * HDIM * 2);    // bf16 pre-BN

  hipMemsetAsync(meta, 0, 64, stream);
  hipMemsetAsync(perm, 0xFF, (size_t)NPAD * 4, stream);
  hist_kernel<<<128, 256, 0, stream>>>(nt, blockHist);
  scan_kernel<<<1, 64, 0, stream>>>(blockHist, blockBase, meta);
  rank_scatter_kernel<<<128, 256, 0, stream>>>(nt, blockBase, meta, perm);
  gather_kernel<<<NPAD / 4, 256, 0, stream>>>(x, perm, xs);

  wtrans_kernel<CIN, HDIM><<<dim3(CIN / 32, HDIM / 32, NTYPE), 256, 0, stream>>>(W1, Wt1);
  wtrans_kernel<HDIM, HDIM><<<dim3(HDIM / 32, HDIM / 32, NTYPE), 256, 0, stream>>>(W2, Wt2);
  wtrans_kernel<HDIM, COUT_F><<<dim3(HDIM / 32, COUT_F / 32, NTYPE), 256, 0, stream>>>(W3, Wt3);

  // Layer 1: GEMM + fused stats (grid 4x264 = 1056; 5 blocks/CU -> one resident round)
  mfma_gemm_kernel<CIN, HDIM, false, true>
      <<<dim3(HDIM / 128, NPAD / 128), 256, 0, stream>>>(xs, Wt1, b1, hb, nullptr, partS, partQ,
                                                         meta, nullptr);
  bn_finalize_kernel<<<(NTYPE * HDIM) / 256, 256, 0, stream>>>(partS, partQ, meta, mean, rstd);
  bn_apply_kernel<<<(NPAD * (HDIM / 8)) / 256, 256, 0, stream>>>(hb, meta, mean, rstd, g1, be1,
                                                                 abuf);
  // Layer 2 (grid 1056)
  mfma_gemm_kernel<HDIM, HDIM, false, true>
      <<<dim3(HDIM / 128, NPAD / 128), 256, 0, stream>>>(abuf, Wt2, b2, hb, nullptr, partS, partQ,
                                                         meta, nullptr);
  bn_finalize_kernel<<<(NTYPE * HDIM) / 256, 256, 0, stream>>>(partS, partQ, meta, mean, rstd);
  bn_apply_kernel<<<(NPAD * (HDIM / 8)) / 256, 256, 0, stream>>>(hb, meta, mean, rstd, g2, be2,
                                                                 abuf);
  // Layer 3 (scatter to d_out, fp32; grid 2x264 = 528)
  mfma_gemm_kernel<HDIM, COUT_F, true, false>
      <<<dim3(COUT_F / 128, NPAD / 128), 256, 0, stream>>>(abuf, Wt3, b3, nullptr, out, nullptr,
                                                           nullptr, meta, perm);
}